// Round 2
// baseline (569.934 us; speedup 1.0000x reference)
//
#include <hip/hip_runtime.h>
#include <stdint.h>

// ---------------------------------------------------------------------------
// gcnmask: out = segment_sum(adj * ((x + segment_sum(drop(sigmoid(A[src]+B[dst]))*x[dst], src)) @ w0)[dst], src)
// where A = x @ w_mask[:128], B = x @ w_mask[128:]  (factored edge GEMM: the
// [E,256]@[256,128] edge GEMM decomposes exactly into two node GEMMs since
// concat(cen,nei)@W = cen@W_top + nei@W_bot and cen/nei are gathers of x).
// Dropout mask must be BIT-EXACT vs jax.random.bernoulli(key(42), 0.4, (E,128)).
// ---------------------------------------------------------------------------

// JAX threefry counter layout. 1 = partitionable (default since JAX 0.4.36):
// bits(i) = o0^o1 of threefry2x32(key, hi(i)=0, lo(i)=i).
// 0 = original: counts=iota split in halves; pair (j, j+H) -> (bits[j], bits[j+H]).
// If validation fails with a LARGE mismatch, flip this to 0 first.
#define THREEFRY_PARTITIONABLE 1

#define NNODES 50000
#define FDIM 128

__device__ __forceinline__ uint32_t rotl32(uint32_t x, int r) {
  return (x << r) | (x >> (32 - r));  // compiler emits v_alignbit_b32
}

// JAX threefry2x32, 20 rounds, verbatim key schedule (jax/_src/prng.py).
__device__ __forceinline__ void threefry2x32(uint32_t k0, uint32_t k1,
                                             uint32_t x0, uint32_t x1,
                                             uint32_t& o0, uint32_t& o1) {
  uint32_t k2 = k0 ^ k1 ^ 0x1BD11BDAu;
  x0 += k0; x1 += k1;
  x0 += x1; x1 = rotl32(x1, 13); x1 ^= x0;
  x0 += x1; x1 = rotl32(x1, 15); x1 ^= x0;
  x0 += x1; x1 = rotl32(x1, 26); x1 ^= x0;
  x0 += x1; x1 = rotl32(x1,  6); x1 ^= x0;
  x0 += k1; x1 += k2 + 1u;
  x0 += x1; x1 = rotl32(x1, 17); x1 ^= x0;
  x0 += x1; x1 = rotl32(x1, 29); x1 ^= x0;
  x0 += x1; x1 = rotl32(x1, 16); x1 ^= x0;
  x0 += x1; x1 = rotl32(x1, 24); x1 ^= x0;
  x0 += k2; x1 += k0 + 2u;
  x0 += x1; x1 = rotl32(x1, 13); x1 ^= x0;
  x0 += x1; x1 = rotl32(x1, 15); x1 ^= x0;
  x0 += x1; x1 = rotl32(x1, 26); x1 ^= x0;
  x0 += x1; x1 = rotl32(x1,  6); x1 ^= x0;
  x0 += k0; x1 += k1 + 3u;
  x0 += x1; x1 = rotl32(x1, 17); x1 ^= x0;
  x0 += x1; x1 = rotl32(x1, 29); x1 ^= x0;
  x0 += x1; x1 = rotl32(x1, 16); x1 ^= x0;
  x0 += x1; x1 = rotl32(x1, 24); x1 ^= x0;
  x0 += k1; x1 += k2 + 4u;
  x0 += x1; x1 = rotl32(x1, 13); x1 ^= x0;
  x0 += x1; x1 = rotl32(x1, 15); x1 ^= x0;
  x0 += x1; x1 = rotl32(x1, 26); x1 ^= x0;
  x0 += x1; x1 = rotl32(x1,  6); x1 ^= x0;
  x0 += k2; x1 += k0 + 5u;
  o0 = x0; o1 = x1;
}

// keep = uniform(bits) < 0.4f, exactly as jax.random.uniform:
// u = bitcast(bits>>9 | 0x3f800000) - 1.0
__device__ __forceinline__ bool keep_drop(uint32_t idx, uint32_t total) {
#if THREEFRY_PARTITIONABLE
  uint32_t o0, o1;
  threefry2x32(0u, 42u, 0u, idx, o0, o1);   // counter hi = 0 (idx < 2^32), lo = idx
  uint32_t bits = o0 ^ o1;
#else
  uint32_t H = total >> 1;
  uint32_t j = (idx < H) ? idx : (idx - H);
  uint32_t o0, o1;
  threefry2x32(0u, 42u, j, j + H, o0, o1);
  uint32_t bits = (idx < H) ? o0 : o1;
#endif
  float u = __uint_as_float((bits >> 9) | 0x3f800000u) - 1.0f;
  return u < 0.4000000059604645f;  // p = f32(1.0 - 0.6)
}

// int64-vs-int32 hedge: harness doc says integer inputs arrive as int32, but the
// reference declares int64. If the buffer is int64 (LE), every odd 32-bit word is 0
// (node ids < 50000 < 2^31). Probe three odd words near the middle.
__device__ __forceinline__ bool detect_i64(const int* p, int n) {
  int i = (n / 2) | 1;
  return p[i] == 0 && p[i + 2] == 0 && p[i + 4] == 0;
}

__device__ __forceinline__ int idx_at(const void* p, int i, bool is64) {
  return is64 ? (int)((const long long*)p)[i] : ((const int*)p)[i];
}

__device__ __forceinline__ int lower_bound_idx(const void* a, int n, bool is64, int v) {
  int lo = 0, hi = n;
  while (lo < hi) {
    int mid = (lo + hi) >> 1;
    if (idx_at(a, mid, is64) < v) lo = mid + 1; else hi = mid;
  }
  return lo;
}

// rowptr[n] = first edge with src >= n, for n in [0, NNODES]
__global__ __launch_bounds__(256) void rowptr_kernel(const void* __restrict__ src, int nE,
                                                     int* __restrict__ rowptr) {
  bool is64 = detect_i64((const int*)src, nE);
  int n = blockIdx.x * blockDim.x + threadIdx.x;
  if (n <= NNODES) rowptr[n] = lower_bound_idx(src, nE, is64, n);
}

// out[N,128] = in[N,128] @ W[128,128] (W row-major, row stride 128)
#define MM_ROWS 8
__global__ __launch_bounds__(128) void matmul128(const float* __restrict__ in,
                                                 const float* __restrict__ W,
                                                 float* __restrict__ out, int nrows) {
  __shared__ float xs[MM_ROWS][FDIM];
  int r0 = blockIdx.x * MM_ROWS;
  int t = threadIdx.x;  // 128 threads, one output column each
  #pragma unroll
  for (int r = 0; r < MM_ROWS; ++r) {
    int row = r0 + r;
    xs[r][t] = (row < nrows) ? in[row * FDIM + t] : 0.0f;
  }
  __syncthreads();
  float acc[MM_ROWS] = {};
  #pragma unroll 4
  for (int k = 0; k < FDIM; ++k) {
    float w = W[k * FDIM + t];
    #pragma unroll
    for (int r = 0; r < MM_ROWS; ++r) acc[r] += xs[r][k] * w;
  }
  #pragma unroll
  for (int r = 0; r < MM_ROWS; ++r) {
    int row = r0 + r;
    if (row < nrows) out[row * FDIM + t] = acc[r];
  }
}

// Per-node segment (src sorted -> contiguous edge range, deterministic order):
// x_new[n] = x[n] + sum_e keep(e,f) * sigmoid(A[n,f]+B[dst_e,f]) * 2.5 * x[dst_e,f]
__global__ __launch_bounds__(128) void edge_agg(const float* __restrict__ x,
                                                const void* __restrict__ dst,
                                                const int* __restrict__ rowptr,
                                                const float* __restrict__ A,
                                                const float* __restrict__ B,
                                                float* __restrict__ x_new, int nE) {
  bool is64 = detect_i64((const int*)dst, nE);
  int n = blockIdx.x;
  int f = threadIdx.x;  // 128 threads = feature dim
  int lo = rowptr[n], hi = rowptr[n + 1];
  float a = A[n * FDIM + f];
  float acc = 0.0f;
  uint32_t total = (uint32_t)nE * (uint32_t)FDIM;
  for (int e = lo; e < hi; ++e) {
    int d = idx_at(dst, e, is64);
    d = min(max(d, 0), NNODES - 1);  // safety clamp (avoid faults if dtype probe is wrong)
    float z = a + B[d * FDIM + f];
    float m = 1.0f / (1.0f + expf(-z));
    uint32_t idx = (uint32_t)e * (uint32_t)FDIM + (uint32_t)f;
    if (keep_drop(idx, total)) acc += (m * 2.5f) * x[d * FDIM + f];
  }
  x_new[n * FDIM + f] = x[n * FDIM + f] + acc;
}

// out[n] = sum_e adj[e] * support[dst_e]
__global__ __launch_bounds__(128) void edge_out(const float* __restrict__ support,
                                                const void* __restrict__ dst,
                                                const int* __restrict__ rowptr,
                                                const float* __restrict__ adj,
                                                float* __restrict__ out, int nE) {
  bool is64 = detect_i64((const int*)dst, nE);
  int n = blockIdx.x;
  int f = threadIdx.x;
  int lo = rowptr[n], hi = rowptr[n + 1];
  float acc = 0.0f;
  for (int e = lo; e < hi; ++e) {
    int d = idx_at(dst, e, is64);
    d = min(max(d, 0), NNODES - 1);
    acc += adj[e] * support[d * FDIM + f];
  }
  out[n * FDIM + f] = acc;
}

extern "C" void kernel_launch(void* const* d_in, const int* in_sizes, int n_in,
                              void* d_out, int out_size, void* d_ws, size_t ws_size,
                              hipStream_t stream) {
  const float* x      = (const float*)d_in[0];
  const void*  src    = d_in[1];
  const void*  dst    = d_in[2];
  const float* adj    = (const float*)d_in[3];
  const float* w_mask = (const float*)d_in[4];
  const float* w0     = (const float*)d_in[5];
  float* out = (float*)d_out;

  int nE = in_sizes[1];
  const size_t NF = (size_t)NNODES * FDIM;

  // ws layout: A | B | x_new | rowptr. support ALIASES A (A is dead after
  // edge_agg; matmul128 writes support strictly after). Total ~77 MB.
  float* A       = (float*)d_ws;
  float* B       = A + NF;
  float* x_new   = B + NF;
  int*   rowptr  = (int*)(x_new + NF);
  float* support = A;

  rowptr_kernel<<<(NNODES + 256) / 256, 256, 0, stream>>>(src, nE, rowptr);
  matmul128<<<(NNODES + MM_ROWS - 1) / MM_ROWS, 128, 0, stream>>>(x, w_mask, A, NNODES);
  matmul128<<<(NNODES + MM_ROWS - 1) / MM_ROWS, 128, 0, stream>>>(x, w_mask + FDIM * FDIM, B, NNODES);
  edge_agg<<<NNODES, 128, 0, stream>>>(x, dst, rowptr, A, B, x_new, nE);
  matmul128<<<(NNODES + MM_ROWS - 1) / MM_ROWS, 128, 0, stream>>>(x_new, w0, support, NNODES);
  edge_out<<<NNODES, 128, 0, stream>>>(support, dst, rowptr, adj, out, nE);
}

// Round 4
// 504.962 us; speedup vs baseline: 1.1287x; 1.1287x over previous
//
#include <hip/hip_runtime.h>
#include <stdint.h>

// ---------------------------------------------------------------------------
// gcnmask, factored form:
//   A = x @ w_mask[:128], B = x @ w_mask[128:]          (node GEMMs, 16x fewer FLOPs
//                                                        than the [E,256]@[256,128] edge GEMM)
//   x_new[n] = x[n] + sum_e keep(e,f)*sigmoid(A[n]+B[dst_e])*2.5*x[dst_e]
//   out = segment_sum(adj * (x_new @ w0)[dst], src)
// Dropout mask is BIT-EXACT vs jax.random.bernoulli(key(42), 0.4, (E,128)):
// threefry2x32 partitionable layout (JAX >= 0.4.36 default) — VERIFIED PASSING r2.
// keep <=> ((o0^o1) < 1717987328u)  [integer form of u<0.4f, exact: u = (bits>>9)*2^-23,
// 0.4f*2^23 = 3355443.25, so u<0.4f <=> bits>>9 <= 3355443 <=> bits < 3355444*512]
// ---------------------------------------------------------------------------

#define NNODES 50000
#define FDIM 128

__device__ __forceinline__ uint32_t rotl32(uint32_t x, int r) {
  return (x << r) | (x >> (32 - r));  // v_alignbit_b32
}

// JAX threefry2x32, 20 rounds, verbatim key schedule (jax/_src/prng.py).
__device__ __forceinline__ void threefry2x32(uint32_t k0, uint32_t k1,
                                             uint32_t x0, uint32_t x1,
                                             uint32_t& o0, uint32_t& o1) {
  uint32_t k2 = k0 ^ k1 ^ 0x1BD11BDAu;
  x0 += k0; x1 += k1;
  x0 += x1; x1 = rotl32(x1, 13); x1 ^= x0;
  x0 += x1; x1 = rotl32(x1, 15); x1 ^= x0;
  x0 += x1; x1 = rotl32(x1, 26); x1 ^= x0;
  x0 += x1; x1 = rotl32(x1,  6); x1 ^= x0;
  x0 += k1; x1 += k2 + 1u;
  x0 += x1; x1 = rotl32(x1, 17); x1 ^= x0;
  x0 += x1; x1 = rotl32(x1, 29); x1 ^= x0;
  x0 += x1; x1 = rotl32(x1, 16); x1 ^= x0;
  x0 += x1; x1 = rotl32(x1, 24); x1 ^= x0;
  x0 += k2; x1 += k0 + 2u;
  x0 += x1; x1 = rotl32(x1, 13); x1 ^= x0;
  x0 += x1; x1 = rotl32(x1, 15); x1 ^= x0;
  x0 += x1; x1 = rotl32(x1, 26); x1 ^= x0;
  x0 += x1; x1 = rotl32(x1,  6); x1 ^= x0;
  x0 += k0; x1 += k1 + 3u;
  x0 += x1; x1 = rotl32(x1, 17); x1 ^= x0;
  x0 += x1; x1 = rotl32(x1, 29); x1 ^= x0;
  x0 += x1; x1 = rotl32(x1, 16); x1 ^= x0;
  x0 += x1; x1 = rotl32(x1, 24); x1 ^= x0;
  x0 += k1; x1 += k2 + 4u;
  x0 += x1; x1 = rotl32(x1, 13); x1 ^= x0;
  x0 += x1; x1 = rotl32(x1, 15); x1 ^= x0;
  x0 += x1; x1 = rotl32(x1, 26); x1 ^= x0;
  x0 += x1; x1 = rotl32(x1,  6); x1 ^= x0;
  x0 += k2; x1 += k0 + 5u;
  o0 = x0; o1 = x1;
}

__device__ __forceinline__ bool keep_drop(uint32_t idx) {
  uint32_t o0, o1;
  threefry2x32(0u, 42u, 0u, idx, o0, o1);  // counter hi=0 (idx < 2^32), lo=idx
  return (o0 ^ o1) < 1717987328u;          // == u < f32(0.4), bit-exact
}

// sigmoid via raw v_exp_f32 / v_rcp_f32 (~1 ulp each; absmax is reassoc-dominated)
__device__ __forceinline__ float sigmoid_f(float z) {
  float e = __builtin_amdgcn_exp2f(z * -1.44269504088896340736f);
  return __builtin_amdgcn_rcpf(1.0f + e);
}

// int64-vs-int32 hedge (validated r2): int64 (LE) buffers have odd 32-bit words == 0.
__device__ __forceinline__ bool detect_i64(const int* p, int n) {
  int i = (n / 2) | 1;
  return p[i] == 0 && p[i + 2] == 0 && p[i + 4] == 0;
}

__device__ __forceinline__ int idx_at(const void* p, int i, bool is64) {
  return is64 ? (int)((const long long*)p)[i] : ((const int*)p)[i];
}

__device__ __forceinline__ int lower_bound_idx(const void* a, int n, bool is64, int v) {
  int lo = 0, hi = n;
  while (lo < hi) {
    int mid = (lo + hi) >> 1;
    if (idx_at(a, mid, is64) < v) lo = mid + 1; else hi = mid;
  }
  return lo;
}

// rowptr[n] = first edge with src >= n, for n in [0, NNODES]
__global__ __launch_bounds__(256) void rowptr_kernel(const void* __restrict__ src, int nE,
                                                     int* __restrict__ rowptr) {
  bool is64 = detect_i64((const int*)src, nE);
  int n = blockIdx.x * blockDim.x + threadIdx.x;
  if (n <= NNODES) rowptr[n] = lower_bound_idx(src, nE, is64, n);
}

// dst -> clamped int32 (moves dtype probe + clamp out of the hot loops)
__global__ __launch_bounds__(256) void cvt_dst(const void* __restrict__ dst, int nE,
                                               int* __restrict__ dst32) {
  bool is64 = detect_i64((const int*)dst, nE);
  int i = blockIdx.x * blockDim.x + threadIdx.x;
  if (i < nE) {
    int d = idx_at(dst, i, is64);
    dst32[i] = min(max(d, 0), NNODES - 1);
  }
}

// Fused A,B = x @ Wtop, x @ Wbot. 16 rows/block, 128 threads (one out-col each).
#define MMR 16
__global__ __launch_bounds__(128) void matmulAB(const float* __restrict__ in,
                                                const float* __restrict__ W,
                                                float* __restrict__ A,
                                                float* __restrict__ B, int nrows) {
  __shared__ float xs[MMR][FDIM];
  int r0 = blockIdx.x * MMR;
  int t = threadIdx.x;
  #pragma unroll
  for (int r = 0; r < MMR; ++r) {
    int row = r0 + r;
    xs[r][t] = (row < nrows) ? in[row * FDIM + t] : 0.0f;
  }
  __syncthreads();
  float accA[MMR] = {}, accB[MMR] = {};
  for (int k = 0; k < FDIM; k += 4) {
    float wa0 = W[(k + 0) * FDIM + t], wa1 = W[(k + 1) * FDIM + t];
    float wa2 = W[(k + 2) * FDIM + t], wa3 = W[(k + 3) * FDIM + t];
    float wb0 = W[(FDIM + k + 0) * FDIM + t], wb1 = W[(FDIM + k + 1) * FDIM + t];
    float wb2 = W[(FDIM + k + 2) * FDIM + t], wb3 = W[(FDIM + k + 3) * FDIM + t];
    #pragma unroll
    for (int r = 0; r < MMR; ++r) {
      float4 xv = *(const float4*)&xs[r][k];  // ds_read_b128, uniform addr (broadcast)
      accA[r] += xv.x * wa0; accA[r] += xv.y * wa1;
      accA[r] += xv.z * wa2; accA[r] += xv.w * wa3;
      accB[r] += xv.x * wb0; accB[r] += xv.y * wb1;
      accB[r] += xv.z * wb2; accB[r] += xv.w * wb3;
    }
  }
  #pragma unroll
  for (int r = 0; r < MMR; ++r) {
    int row = r0 + r;
    if (row < nrows) { A[row * FDIM + t] = accA[r]; B[row * FDIM + t] = accB[r]; }
  }
}

// out[N,128] = in[N,128] @ W[128,128], 16-row register blocking
__global__ __launch_bounds__(128) void matmul16(const float* __restrict__ in,
                                                const float* __restrict__ W,
                                                float* __restrict__ out, int nrows) {
  __shared__ float xs[MMR][FDIM];
  int r0 = blockIdx.x * MMR;
  int t = threadIdx.x;
  #pragma unroll
  for (int r = 0; r < MMR; ++r) {
    int row = r0 + r;
    xs[r][t] = (row < nrows) ? in[row * FDIM + t] : 0.0f;
  }
  __syncthreads();
  float acc[MMR] = {};
  for (int k = 0; k < FDIM; k += 4) {
    float w0 = W[(k + 0) * FDIM + t], w1 = W[(k + 1) * FDIM + t];
    float w2 = W[(k + 2) * FDIM + t], w3 = W[(k + 3) * FDIM + t];
    #pragma unroll
    for (int r = 0; r < MMR; ++r) {
      float4 xv = *(const float4*)&xs[r][k];
      acc[r] += xv.x * w0; acc[r] += xv.y * w1;
      acc[r] += xv.z * w2; acc[r] += xv.w * w3;
    }
  }
  #pragma unroll
  for (int r = 0; r < MMR; ++r) {
    int row = r0 + r;
    if (row < nrows) out[row * FDIM + t] = acc[r];
  }
}

// Per-node segment (src sorted), 4-way unrolled: 4 independent threefry chains
// + 4 gathers in flight per thread to cover VALU dep latency + L2/L3 latency.
__global__ __launch_bounds__(128) void edge_agg(const float* __restrict__ x,
                                                const int* __restrict__ dst32,
                                                const int* __restrict__ rowptr,
                                                const float* __restrict__ A,
                                                const float* __restrict__ B,
                                                float* __restrict__ x_new) {
  int n = blockIdx.x;
  int f = threadIdx.x;
  int lo = rowptr[n], hi = rowptr[n + 1];
  const float* Bf = B + f;
  const float* xf = x + f;
  float a = A[(n << 7) + f];
  float acc0 = 0.f, acc1 = 0.f, acc2 = 0.f, acc3 = 0.f;
  uint32_t idx = ((uint32_t)lo << 7) + (uint32_t)f;
  int e = lo;
  for (; e + 4 <= hi; e += 4, idx += 512u) {
    int d0 = dst32[e + 0], d1 = dst32[e + 1], d2 = dst32[e + 2], d3 = dst32[e + 3];
    float b0 = Bf[d0 << 7], xv0 = xf[d0 << 7];
    float b1 = Bf[d1 << 7], xv1 = xf[d1 << 7];
    float b2 = Bf[d2 << 7], xv2 = xf[d2 << 7];
    float b3 = Bf[d3 << 7], xv3 = xf[d3 << 7];
    bool k0 = keep_drop(idx);
    bool k1 = keep_drop(idx + 128u);
    bool k2 = keep_drop(idx + 256u);
    bool k3 = keep_drop(idx + 384u);
    float m0 = sigmoid_f(a + b0), m1 = sigmoid_f(a + b1);
    float m2 = sigmoid_f(a + b2), m3 = sigmoid_f(a + b3);
    acc0 += k0 ? (m0 * 2.5f) * xv0 : 0.0f;
    acc1 += k1 ? (m1 * 2.5f) * xv1 : 0.0f;
    acc2 += k2 ? (m2 * 2.5f) * xv2 : 0.0f;
    acc3 += k3 ? (m3 * 2.5f) * xv3 : 0.0f;
  }
  for (; e < hi; ++e, idx += 128u) {
    int d = dst32[e];
    float m = sigmoid_f(a + Bf[d << 7]);
    if (keep_drop(idx)) acc0 += (m * 2.5f) * xf[d << 7];
  }
  float acc = (acc0 + acc1) + (acc2 + acc3);
  x_new[(n << 7) + f] = x[(n << 7) + f] + acc;
}

// out[n] = sum_e adj[e] * support[dst_e], 4-way unrolled for gather MLP
__global__ __launch_bounds__(128) void edge_out(const float* __restrict__ support,
                                                const int* __restrict__ dst32,
                                                const int* __restrict__ rowptr,
                                                const float* __restrict__ adj,
                                                float* __restrict__ out) {
  int n = blockIdx.x;
  int f = threadIdx.x;
  int lo = rowptr[n], hi = rowptr[n + 1];
  const float* Sf = support + f;
  float a0 = 0.f, a1 = 0.f, a2 = 0.f, a3 = 0.f;
  int e = lo;
  for (; e + 4 <= hi; e += 4) {
    int d0 = dst32[e + 0], d1 = dst32[e + 1], d2 = dst32[e + 2], d3 = dst32[e + 3];
    float w0 = adj[e + 0], w1 = adj[e + 1], w2 = adj[e + 2], w3 = adj[e + 3];
    a0 += w0 * Sf[d0 << 7];
    a1 += w1 * Sf[d1 << 7];
    a2 += w2 * Sf[d2 << 7];
    a3 += w3 * Sf[d3 << 7];
  }
  for (; e < hi; ++e) a0 += adj[e] * Sf[dst32[e] << 7];
  out[(n << 7) + f] = (a0 + a1) + (a2 + a3);
}

extern "C" void kernel_launch(void* const* d_in, const int* in_sizes, int n_in,
                              void* d_out, int out_size, void* d_ws, size_t ws_size,
                              hipStream_t stream) {
  const float* x      = (const float*)d_in[0];
  const void*  src    = d_in[1];
  const void*  dst    = d_in[2];
  const float* adj    = (const float*)d_in[3];
  const float* w_mask = (const float*)d_in[4];
  const float* w0     = (const float*)d_in[5];
  float* out = (float*)d_out;

  int nE = in_sizes[1];
  const size_t NF = (size_t)NNODES * FDIM;

  // ws: A | B | x_new | rowptr(50001) | dst32(nE). support aliases A (dead after
  // edge_agg). Total ~80.3 MB (r2 used 77 MB and passed).
  float* A       = (float*)d_ws;
  float* B       = A + NF;
  float* x_new   = B + NF;
  int*   rowptr  = (int*)(x_new + NF);
  int*   dst32   = rowptr + (NNODES + 1);
  float* support = A;

  rowptr_kernel<<<(NNODES + 256) / 256, 256, 0, stream>>>(src, nE, rowptr);
  cvt_dst<<<(nE + 255) / 256, 256, 0, stream>>>(dst, nE, dst32);
  matmulAB<<<(NNODES + MMR - 1) / MMR, 128, 0, stream>>>(x, w_mask, A, B, NNODES);
  edge_agg<<<NNODES, 128, 0, stream>>>(x, dst32, rowptr, A, B, x_new);
  matmul16<<<(NNODES + MMR - 1) / MMR, 128, 0, stream>>>(x_new, w0, support, NNODES);
  edge_out<<<NNODES, 128, 0, stream>>>(support, dst32, rowptr, adj, out);
}